// Round 3
// baseline (482.093 us; speedup 1.0000x reference)
//
#include <hip/hip_runtime.h>

#define MM    12
#define TSOL  64
#define NXX   256
#define NYY   256
#define NTT   50
#define NOUTT 256
#define IPB   2     // rows per wave; block = 4 waves x IPB rows = 8 rows

// Packed 3-tap stencil table: g_tab3[(tap*MM + m)*NOUTT + k], tap in {m1,c,p1}.
// out[k] = wm1*src[k-1] + wc*src[k] + wp1*src[k+1]  (iy[m][k] in {k-1,k}).
__device__ float g_tab3[3 * MM * NOUTT];

// grid: MM blocks x 256 threads. Block m computes table row m.
__global__ __launch_bounds__(256) void ai_setup_kernel(
    const float* __restrict__ params,
    const float* __restrict__ Wq, const float* __restrict__ bq,
    const float* __restrict__ Wk, const float* __restrict__ bk)
{
    const int k = threadIdx.x;
    const int m = blockIdx.x;

    __shared__ float s_attn[MM][4];
    __shared__ float s_sw[MM];
    __shared__ float s_wm;
    __shared__ float s_ys[NYY];

    if (k < MM) {
        float ly = params[k * 3 + 0];
        float p0 = (ly - 30.0f) / 90.0f;
        float p1 = params[k * 3 + 1] / 0.0029f;
        float p2 = params[k * 3 + 2] / 0.0018f;
        const float t0 = 0.5f;                 // (75-30)/90 exact
        const float t1 = 0.001f / 0.0029f;
        const float t2 = 0.0001f / 0.0018f;
        for (int h = 0; h < 4; ++h) {
            float acc = 0.0f;
            for (int d = 0; d < 8; ++d) {
                int o = h * 8 + d;
                float q  = t0 * Wq[o * 3 + 0] + t1 * Wq[o * 3 + 1] + t2 * Wq[o * 3 + 2] + bq[o];
                float kv = p0 * Wk[o * 3 + 0] + p1 * Wk[o * 3 + 1] + p2 * Wk[o * 3 + 2] + bk[o];
                acc += kv * q;
            }
            s_attn[k][h] = acc * 0.35355339059327373f;  // 1/sqrt(8)
        }
        float d0 = (p0 - t0) / 0.25f;
        float d1 = (p1 - t1) / 0.25f;
        float d2 = (p2 - t2) / 0.25f;
        s_sw[k] = expf(-(d0 * d0 + d1 * d1 + d2 * d2) * 0.5f);
    }
    __syncthreads();

    if (k == 0) {
        float aw[MM];
        for (int j = 0; j < MM; ++j) aw[j] = 0.0f;
        for (int h = 0; h < 4; ++h) {               // softmax over m, per head
            float mx = s_attn[0][h];
            for (int j = 1; j < MM; ++j) mx = fmaxf(mx, s_attn[j][h]);
            float e[MM]; float sum = 0.0f;
            for (int j = 0; j < MM; ++j) { e[j] = expf(s_attn[j][h] - mx); sum += e[j]; }
            for (int j = 0; j < MM; ++j) aw[j] += e[j] / sum;
        }
        float swsum = 0.0f;
        for (int j = 0; j < MM; ++j) swsum += s_sw[j];
        float wj[MM]; float wsum = 0.0f;
        for (int j = 0; j < MM; ++j) {
            wj[j] = (aw[j] * 0.25f) * (s_sw[j] / swsum);
            wsum += wj[j];
        }
        s_wm = wj[m] / wsum;
    }

    // ys row for this m — EXACT fp32 op sequence of the reference:
    // ys[j] = fl( fl(l01[j]*ly) * fl(75/ly) ),  l01[j] = fl(j * fl(1/255))
    {
        float ly  = params[m * 3 + 0];
        float inv = 75.0f / ly;                    // IEEE divide (no fast-math)
        float l01 = (float)k * (1.0f / 255.0f);
        s_ys[k] = (l01 * ly) * inv;
    }
    __syncthreads();

    float w  = s_wm;
    float yq = (float)k * (75.0f / 255.0f);        // rounds to exactly 75.0 at k=255
    // upper_bound: largest j with ys[j] <= yq  (== searchsorted 'right' - 1)
    int l = 0, r = NYY;
    while (l < r) { int mid = (l + r) >> 1; if (s_ys[mid] <= yq) l = mid + 1; else r = mid; }
    int iy = l - 1;
    iy = iy < 0 ? 0 : (iy > NYY - 2 ? NYY - 2 : iy);
    float ty  = (yq - s_ys[iy]) / (s_ys[iy + 1] - s_ys[iy]);
    bool  inb = (yq >= s_ys[0]) && (yq <= s_ys[NYY - 1]);   // the k=255 knife edge
    float a = inb ? w * (1.0f - ty) : 0.0f;        // weight on src[iy]
    float b = inb ? w * ty          : 0.0f;        // weight on src[iy+1]
    // ys monotone ~ k*(75/255)*(1 +- 2ulp) => iy is exactly k or k-1
    bool sel = (iy == k);                          // taps (0,a,b) else (a,b,0)
    g_tab3[(0 * MM + m) * NOUTT + k] = sel ? 0.0f : a;   // wm1
    g_tab3[(1 * MM + m) * NOUTT + k] = sel ? a    : b;   // wc
    g_tab3[(2 * MM + m) * NOUTT + k] = sel ? b    : 0.0f;// wp1
}

// grid: (NOUTT/(4*IPB), NTT), block 256 = 4 waves. Wave wv, pass r handles
// output row i = 8*blockIdx.x + 4*r + wv (4 waves read 4 consecutive rows =
// 4KB contiguous per slab per pass). Weights live in LDS (ds_read -> lgkmcnt,
// NOT the vmcnt FIFO), and the 12 source loads per channel are issued as one
// same-class batch into st[12] so the compiler can consume them with
// progressive vmcnt(11)..(0) instead of draining misses per-m.
__global__ __launch_bounds__(256) void ai_resample_kernel(
    const float* __restrict__ c1, const float* __restrict__ c2,
    float* __restrict__ out)
{
    __shared__ float s_t[3 * MM * NOUTT];     // 36 KB -> 4 blocks/CU

    const int tid  = threadIdx.x;
    const int lane = tid & 63;
    const int wv   = tid >> 6;
    const int t    = blockIdx.y;
    const int i0   = blockIdx.x * (4 * IPB);
    int tsrc = (t * TSOL) / (NTT - 1);        // floor(t*64/49), fp-robust
    if (tsrc > TSOL - 1) tsrc = TSOL - 1;
    const int k0 = lane * 4;

    // Stage the 36 KB weight table into LDS via global_load_lds DMA:
    // zero dest VGPRs, one vmcnt drain at the single block-start barrier.
    // Per chunk c: wave base (c*1024 + wv*256) floats, lane adds 16 B.
#pragma unroll
    for (int c = 0; c < 9; ++c) {
        const float* gp = g_tab3 + c * 1024 + wv * 256 + lane * 4;
        float*       lp = s_t    + c * 1024 + wv * 256;   // wave-uniform base
        __builtin_amdgcn_global_load_lds(
            (const __attribute__((address_space(1))) void*)gp,
            (__attribute__((address_space(3))) void*)lp, 16, 0, 0);
    }
    __syncthreads();

#pragma unroll
    for (int r = 0; r < IPB; ++r) {
        const int i = i0 + r * 4 + wv;

        unsigned int off[MM];                 // same offset for c1 and c2
#pragma unroll
        for (int m = 0; m < MM; ++m)
            off[m] = (((unsigned int)(m * TSOL + tsrc) * NXX) + (unsigned int)i) * NYY
                   + (unsigned int)k0;

        float4 acc1 = {0.f, 0.f, 0.f, 0.f};
        float4 acc2 = {0.f, 0.f, 0.f, 0.f};
        float4 st[MM];

        // ---- channel 1: issue all 12 misses, then consume in order ----
#pragma unroll
        for (int m = 0; m < MM; ++m) st[m] = *(const float4*)(c1 + off[m]);
#pragma unroll
        for (int m = 0; m < MM; ++m) {
            const float4 wm1 = *(const float4*)&s_t[(0 * MM + m) * NOUTT + k0];
            const float4 wc  = *(const float4*)&s_t[(1 * MM + m) * NOUTT + k0];
            const float4 wp1 = *(const float4*)&s_t[(2 * MM + m) * NOUTT + k0];
            float lft = __shfl_up(st[m].w, 1);     // src[k0-1] (k=0: weight 0)
            float rgt = __shfl_down(st[m].x, 1);   // src[k0+4] (k=255: weight 0)
            acc1.x += wm1.x * lft     + wc.x * st[m].x + wp1.x * st[m].y;
            acc1.y += wm1.y * st[m].x + wc.y * st[m].y + wp1.y * st[m].z;
            acc1.z += wm1.z * st[m].y + wc.z * st[m].z + wp1.z * st[m].w;
            acc1.w += wm1.w * st[m].z + wc.w * st[m].w + wp1.w * rgt;
        }

        // ---- channel 2 ----
#pragma unroll
        for (int m = 0; m < MM; ++m) st[m] = *(const float4*)(c2 + off[m]);
#pragma unroll
        for (int m = 0; m < MM; ++m) {
            const float4 wm1 = *(const float4*)&s_t[(0 * MM + m) * NOUTT + k0];
            const float4 wc  = *(const float4*)&s_t[(1 * MM + m) * NOUTT + k0];
            const float4 wp1 = *(const float4*)&s_t[(2 * MM + m) * NOUTT + k0];
            float lft = __shfl_up(st[m].w, 1);
            float rgt = __shfl_down(st[m].x, 1);
            acc2.x += wm1.x * lft     + wc.x * st[m].x + wp1.x * st[m].y;
            acc2.y += wm1.y * st[m].x + wc.y * st[m].y + wp1.y * st[m].z;
            acc2.z += wm1.z * st[m].y + wc.z * st[m].z + wp1.z * st[m].w;
            acc2.w += wm1.w * st[m].z + wc.w * st[m].w + wp1.w * rgt;
        }

        if (lane == 0)  acc1.x = 0.001f;      // c1[:,:,0]  = C_CU_TARGET
        if (lane == 63) acc2.w = 0.0001f;     // c2[:,:,-1] = C_NI_TARGET

        *(float4*)&out[((size_t)t * NOUTT + (size_t)i) * NOUTT + (size_t)k0] = acc1;
        *(float4*)&out[((size_t)(NTT + t) * NOUTT + (size_t)i) * NOUTT + (size_t)k0] = acc2;
    }
}

extern "C" void kernel_launch(void* const* d_in, const int* in_sizes, int n_in,
                              void* d_out, int out_size, void* d_ws, size_t ws_size,
                              hipStream_t stream) {
    const float* params = (const float*)d_in[0];
    const float* c1     = (const float*)d_in[1];
    const float* c2     = (const float*)d_in[2];
    const float* Wq     = (const float*)d_in[3];
    const float* bq     = (const float*)d_in[4];
    const float* Wk     = (const float*)d_in[5];
    const float* bk     = (const float*)d_in[6];
    float* out = (float*)d_out;

    ai_setup_kernel<<<dim3(MM), dim3(256), 0, stream>>>(params, Wq, bq, Wk, bk);
    ai_resample_kernel<<<dim3(NOUTT / (4 * IPB), NTT), dim3(256), 0, stream>>>(c1, c2, out);
}

// Round 4
// 433.436 us; speedup vs baseline: 1.1123x; 1.1123x over previous
//
#include <hip/hip_runtime.h>

#define MM    12
#define TSOL  64
#define NXX   256
#define NYY   256
#define NTT   50
#define NOUTT 256
#define TPW   5     // t-rows per wave (amortizes the correction table)

// Compressed stencil: per (m,k) ONE float c. Contribution of source m at
// output k:  w[m]*src[k] + |c|*(src[k+sgn(c)] - src[k]),  where
// c = (iy==k) ? +w*ty : -(w*(1-ty)). Exact up to 1ulp regrouping (<=2e-10).
// w[m] is a per-m scalar; k=255 uses w255[m] (inb knife edge).
__device__ float g_c[MM * NOUTT];
__device__ float g_w[MM];
__device__ float g_w255[MM];

// grid: MM blocks x 256 threads. Block m computes table row m.
__global__ __launch_bounds__(256) void ai_setup_kernel(
    const float* __restrict__ params,
    const float* __restrict__ Wq, const float* __restrict__ bq,
    const float* __restrict__ Wk, const float* __restrict__ bk)
{
    const int k = threadIdx.x;
    const int m = blockIdx.x;

    __shared__ float s_attn[MM][4];
    __shared__ float s_sw[MM];
    __shared__ float s_wm;
    __shared__ float s_ys[NYY];

    if (k < MM) {
        float ly = params[k * 3 + 0];
        float p0 = (ly - 30.0f) / 90.0f;
        float p1 = params[k * 3 + 1] / 0.0029f;
        float p2 = params[k * 3 + 2] / 0.0018f;
        const float t0 = 0.5f;                 // (75-30)/90 exact
        const float t1 = 0.001f / 0.0029f;
        const float t2 = 0.0001f / 0.0018f;
        for (int h = 0; h < 4; ++h) {
            float acc = 0.0f;
            for (int d = 0; d < 8; ++d) {
                int o = h * 8 + d;
                float q  = t0 * Wq[o * 3 + 0] + t1 * Wq[o * 3 + 1] + t2 * Wq[o * 3 + 2] + bq[o];
                float kv = p0 * Wk[o * 3 + 0] + p1 * Wk[o * 3 + 1] + p2 * Wk[o * 3 + 2] + bk[o];
                acc += kv * q;
            }
            s_attn[k][h] = acc * 0.35355339059327373f;  // 1/sqrt(8)
        }
        float d0 = (p0 - t0) / 0.25f;
        float d1 = (p1 - t1) / 0.25f;
        float d2 = (p2 - t2) / 0.25f;
        s_sw[k] = expf(-(d0 * d0 + d1 * d1 + d2 * d2) * 0.5f);
    }
    __syncthreads();

    if (k == 0) {
        float aw[MM];
        for (int j = 0; j < MM; ++j) aw[j] = 0.0f;
        for (int h = 0; h < 4; ++h) {               // softmax over m, per head
            float mx = s_attn[0][h];
            for (int j = 1; j < MM; ++j) mx = fmaxf(mx, s_attn[j][h]);
            float e[MM]; float sum = 0.0f;
            for (int j = 0; j < MM; ++j) { e[j] = expf(s_attn[j][h] - mx); sum += e[j]; }
            for (int j = 0; j < MM; ++j) aw[j] += e[j] / sum;
        }
        float swsum = 0.0f;
        for (int j = 0; j < MM; ++j) swsum += s_sw[j];
        float wj[MM]; float wsum = 0.0f;
        for (int j = 0; j < MM; ++j) {
            wj[j] = (aw[j] * 0.25f) * (s_sw[j] / swsum);
            wsum += wj[j];
        }
        s_wm = wj[m] / wsum;
    }

    // ys row for this m — EXACT fp32 op sequence of the reference:
    // ys[j] = fl( fl(l01[j]*ly) * fl(75/ly) ),  l01[j] = fl(j * fl(1/255))
    {
        float ly  = params[m * 3 + 0];
        float inv = 75.0f / ly;                    // IEEE divide (no fast-math)
        float l01 = (float)k * (1.0f / 255.0f);
        s_ys[k] = (l01 * ly) * inv;
    }
    __syncthreads();

    float w  = s_wm;
    float yq = (float)k * (75.0f / 255.0f);        // rounds to exactly 75.0 at k=255
    // upper_bound: largest j with ys[j] <= yq  (== searchsorted 'right' - 1)
    int l = 0, r = NYY;
    while (l < r) { int mid = (l + r) >> 1; if (s_ys[mid] <= yq) l = mid + 1; else r = mid; }
    int iy = l - 1;
    iy = iy < 0 ? 0 : (iy > NYY - 2 ? NYY - 2 : iy);
    float ty  = (yq - s_ys[iy]) / (s_ys[iy + 1] - s_ys[iy]);
    bool  inb = (yq >= s_ys[0]) && (yq <= s_ys[NYY - 1]);   // the k=255 knife edge
    float a = inb ? w * (1.0f - ty) : 0.0f;        // weight on src[iy]
    float b = inb ? w * ty          : 0.0f;        // weight on src[iy+1]
    // iy is exactly k or k-1 (ys ~= k*75/255 up to 2 ulp, monotone).
    bool sel = (iy == k);
    // sign of c encodes neighbor: +c -> k+1 (weight b), -c -> k-1 (weight a).
    g_c[m * NOUTT + k] = sel ? b : -a;             // -0.0f keeps direction
    if (k == 0)   g_w[m]    = w;                   // inb always true for k<255
    if (k == 255) g_w255[m] = inb ? w : 0.0f;
}

// grid: (NOUTT/4, NTT/TPW), block 256 = 4 waves. Wave wv owns output row
// i = 4*bx + wv (full 256 k's, lane l -> k=4l..4l+3) and loops TPW t-values.
// Correction table (12 float4/lane) loaded ONCE per wave; per-m base weights
// are scalars. Per t-row: 12 c1 float4 loads batched (progressive vmcnt),
// consumed in issue order, then same for c2. No LDS, no gathers.
__global__ __launch_bounds__(256, 3) void ai_resample_kernel(
    const float* __restrict__ c1, const float* __restrict__ c2,
    float* __restrict__ out)
{
    const int tid  = threadIdx.x;
    const int lane = tid & 63;
    const int wv   = tid >> 6;
    const int i    = blockIdx.x * 4 + wv;
    const int tb   = blockIdx.y * TPW;
    const int k0   = lane * 4;
    const bool l63 = (lane == 63);

    // Per-lane correction table: 12 float4 = 48 VGPR, loaded once.
    float4 cm[MM];
#pragma unroll
    for (int m = 0; m < MM; ++m) cm[m] = *(const float4*)&g_c[m * NOUTT + k0];
    // Per-m scalar weights (uniform address -> scalar loads).
    float wmv[MM], w2v[MM];
#pragma unroll
    for (int m = 0; m < MM; ++m) { wmv[m] = g_w[m]; w2v[m] = g_w255[m]; }

#pragma unroll 1
    for (int j = 0; j < TPW; ++j) {
        const int t = tb + j;
        int tsrc = (t * TSOL) / (NTT - 1);     // floor, fp-robust
        if (tsrc > TSOL - 1) tsrc = TSOL - 1;
        const size_t rowoff = (size_t)tsrc * (NXX * NYY) + (size_t)i * NYY + (size_t)k0;

        float4 acc1 = {0.f, 0.f, 0.f, 0.f};
        float4 acc2 = {0.f, 0.f, 0.f, 0.f};
        float4 st[MM];

        // ---- channel 1: batch 12 loads, consume in issue order ----
#pragma unroll
        for (int m = 0; m < MM; ++m)
            st[m] = *(const float4*)(c1 + (size_t)m * (TSOL * NXX * NYY) + rowoff);
#pragma unroll
        for (int m = 0; m < MM; ++m) {
            float4 s = st[m];
            float lft = __shfl_up(s.w, 1);     // src[k0-1]; lane0: dead (c.x>=+0)
            float rgt = __shfl_down(s.x, 1);   // src[k0+4]; lane63: dead (c.w<=-0)
            float4 c  = cm[m];
            float wm_ = wmv[m];
            float w_w = l63 ? w2v[m] : wm_;    // k=255 knife edge
            acc1.x += wm_ * s.x + fabsf(c.x) * (((__float_as_int(c.x) >= 0) ? s.y : lft) - s.x);
            acc1.y += wm_ * s.y + fabsf(c.y) * (((__float_as_int(c.y) >= 0) ? s.z : s.x) - s.y);
            acc1.z += wm_ * s.z + fabsf(c.z) * (((__float_as_int(c.z) >= 0) ? s.w : s.y) - s.z);
            acc1.w += w_w * s.w + fabsf(c.w) * (((__float_as_int(c.w) >= 0) ? rgt : s.z) - s.w);
        }

        // ---- channel 2 ----
#pragma unroll
        for (int m = 0; m < MM; ++m)
            st[m] = *(const float4*)(c2 + (size_t)m * (TSOL * NXX * NYY) + rowoff);
#pragma unroll
        for (int m = 0; m < MM; ++m) {
            float4 s = st[m];
            float lft = __shfl_up(s.w, 1);
            float rgt = __shfl_down(s.x, 1);
            float4 c  = cm[m];
            float wm_ = wmv[m];
            float w_w = l63 ? w2v[m] : wm_;
            acc2.x += wm_ * s.x + fabsf(c.x) * (((__float_as_int(c.x) >= 0) ? s.y : lft) - s.x);
            acc2.y += wm_ * s.y + fabsf(c.y) * (((__float_as_int(c.y) >= 0) ? s.z : s.x) - s.y);
            acc2.z += wm_ * s.z + fabsf(c.z) * (((__float_as_int(c.z) >= 0) ? s.w : s.y) - s.z);
            acc2.w += w_w * s.w + fabsf(c.w) * (((__float_as_int(c.w) >= 0) ? rgt : s.z) - s.w);
        }

        if (lane == 0) acc1.x = 0.001f;        // c1[:,:,0]  = C_CU_TARGET
        if (l63)       acc2.w = 0.0001f;       // c2[:,:,-1] = C_NI_TARGET

        *(float4*)&out[((size_t)t * NOUTT + (size_t)i) * NOUTT + (size_t)k0] = acc1;
        *(float4*)&out[((size_t)(NTT + t) * NOUTT + (size_t)i) * NOUTT + (size_t)k0] = acc2;
    }
}

extern "C" void kernel_launch(void* const* d_in, const int* in_sizes, int n_in,
                              void* d_out, int out_size, void* d_ws, size_t ws_size,
                              hipStream_t stream) {
    const float* params = (const float*)d_in[0];
    const float* c1     = (const float*)d_in[1];
    const float* c2     = (const float*)d_in[2];
    const float* Wq     = (const float*)d_in[3];
    const float* bq     = (const float*)d_in[4];
    const float* Wk     = (const float*)d_in[5];
    const float* bk     = (const float*)d_in[6];
    float* out = (float*)d_out;

    ai_setup_kernel<<<dim3(MM), dim3(256), 0, stream>>>(params, Wq, bq, Wk, bk);
    ai_resample_kernel<<<dim3(NOUTT / 4, NTT / TPW), dim3(256), 0, stream>>>(c1, c2, out);
}

// Round 5
// 408.993 us; speedup vs baseline: 1.1787x; 1.0598x over previous
//
#include <hip/hip_runtime.h>

#define MM    12
#define TSOL  64
#define NXX   256
#define NYY   256
#define NTT   50
#define NOUTT 256

// Compressed stencil: per (m,k) ONE float c. Contribution of source m at
// output k:  w[m]*src[k] + |c|*(src[k+sgn(c)] - src[k]),  where
// c = (iy==k) ? +w*ty : -(w*(1-ty)). Exact up to 1ulp regrouping (<=2e-10).
// w[m] is a per-m scalar; k=255 uses w255[m] (inb knife edge).
__device__ float g_c[MM * NOUTT];
__device__ float g_w[MM];
__device__ float g_w255[MM];

// grid: MM blocks x 256 threads. Block m computes table row m.
__global__ __launch_bounds__(256) void ai_setup_kernel(
    const float* __restrict__ params,
    const float* __restrict__ Wq, const float* __restrict__ bq,
    const float* __restrict__ Wk, const float* __restrict__ bk)
{
    const int k = threadIdx.x;
    const int m = blockIdx.x;

    __shared__ float s_attn[MM][4];
    __shared__ float s_sw[MM];
    __shared__ float s_wm;
    __shared__ float s_ys[NYY];

    if (k < MM) {
        float ly = params[k * 3 + 0];
        float p0 = (ly - 30.0f) / 90.0f;
        float p1 = params[k * 3 + 1] / 0.0029f;
        float p2 = params[k * 3 + 2] / 0.0018f;
        const float t0 = 0.5f;                 // (75-30)/90 exact
        const float t1 = 0.001f / 0.0029f;
        const float t2 = 0.0001f / 0.0018f;
        for (int h = 0; h < 4; ++h) {
            float acc = 0.0f;
            for (int d = 0; d < 8; ++d) {
                int o = h * 8 + d;
                float q  = t0 * Wq[o * 3 + 0] + t1 * Wq[o * 3 + 1] + t2 * Wq[o * 3 + 2] + bq[o];
                float kv = p0 * Wk[o * 3 + 0] + p1 * Wk[o * 3 + 1] + p2 * Wk[o * 3 + 2] + bk[o];
                acc += kv * q;
            }
            s_attn[k][h] = acc * 0.35355339059327373f;  // 1/sqrt(8)
        }
        float d0 = (p0 - t0) / 0.25f;
        float d1 = (p1 - t1) / 0.25f;
        float d2 = (p2 - t2) / 0.25f;
        s_sw[k] = expf(-(d0 * d0 + d1 * d1 + d2 * d2) * 0.5f);
    }
    __syncthreads();

    if (k == 0) {
        float aw[MM];
        for (int j = 0; j < MM; ++j) aw[j] = 0.0f;
        for (int h = 0; h < 4; ++h) {               // softmax over m, per head
            float mx = s_attn[0][h];
            for (int j = 1; j < MM; ++j) mx = fmaxf(mx, s_attn[j][h]);
            float e[MM]; float sum = 0.0f;
            for (int j = 0; j < MM; ++j) { e[j] = expf(s_attn[j][h] - mx); sum += e[j]; }
            for (int j = 0; j < MM; ++j) aw[j] += e[j] / sum;
        }
        float swsum = 0.0f;
        for (int j = 0; j < MM; ++j) swsum += s_sw[j];
        float wj[MM]; float wsum = 0.0f;
        for (int j = 0; j < MM; ++j) {
            wj[j] = (aw[j] * 0.25f) * (s_sw[j] / swsum);
            wsum += wj[j];
        }
        s_wm = wj[m] / wsum;
    }

    // ys row for this m — EXACT fp32 op sequence of the reference:
    // ys[j] = fl( fl(l01[j]*ly) * fl(75/ly) ),  l01[j] = fl(j * fl(1/255))
    {
        float ly  = params[m * 3 + 0];
        float inv = 75.0f / ly;                    // IEEE divide (no fast-math)
        float l01 = (float)k * (1.0f / 255.0f);
        s_ys[k] = (l01 * ly) * inv;
    }
    __syncthreads();

    float w  = s_wm;
    float yq = (float)k * (75.0f / 255.0f);        // rounds to exactly 75.0 at k=255
    // upper_bound: largest j with ys[j] <= yq  (== searchsorted 'right' - 1)
    int l = 0, r = NYY;
    while (l < r) { int mid = (l + r) >> 1; if (s_ys[mid] <= yq) l = mid + 1; else r = mid; }
    int iy = l - 1;
    iy = iy < 0 ? 0 : (iy > NYY - 2 ? NYY - 2 : iy);
    float ty  = (yq - s_ys[iy]) / (s_ys[iy + 1] - s_ys[iy]);
    bool  inb = (yq >= s_ys[0]) && (yq <= s_ys[NYY - 1]);   // the k=255 knife edge
    float a = inb ? w * (1.0f - ty) : 0.0f;        // weight on src[iy]
    float b = inb ? w * ty          : 0.0f;        // weight on src[iy+1]
    // iy is exactly k or k-1 (ys ~= k*75/255 up to 2 ulp, monotone).
    bool sel = (iy == k);
    // sign of c encodes neighbor: +c -> k+1 (weight b), -c -> k-1 (weight a).
    g_c[m * NOUTT + k] = sel ? b : -a;             // -0.0f keeps direction
    if (k == 0)   g_w[m]    = w;                   // inb always true for k<255
    if (k == 255) g_w255[m] = inb ? w : 0.0f;
}

// grid: (NOUTT/4, NTT) = R2's proven shape (FETCH ~154MB, 12800 waves).
// Wave wv owns output row i = 4*bx+wv for t = by, all 256 k's (lane l ->
// k=4l..4l+3). The 12KB compressed table is DMA'd to LDS once per block
// (table reads move to the LDS pipe, off the VMEM return path); src loads
// are batched 12-deep per channel (progressive vmcnt), issued before the
// staging barrier so the drain overlaps the first channel's misses.
// VMEM return bytes/wave: 26KB vs R2's 62KB.
__global__ __launch_bounds__(256) void ai_resample_kernel(
    const float* __restrict__ c1, const float* __restrict__ c2,
    float* __restrict__ out)
{
    __shared__ float s_c[MM * NOUTT];          // 12 KB

    const int tid  = threadIdx.x;
    const int lane = tid & 63;
    const int wv   = tid >> 6;
    const int t    = blockIdx.y;
    const int i    = blockIdx.x * 4 + wv;
    int tsrc = (t * TSOL) / (NTT - 1);         // floor(t*64/49), fp-robust
    if (tsrc > TSOL - 1) tsrc = TSOL - 1;
    const int k0   = lane * 4;
    const bool l63 = (lane == 63);

    // Stage 12KB table: 3 chunks x (4 waves x 1KB), wave-uniform LDS base.
#pragma unroll
    for (int c = 0; c < 3; ++c) {
        const float* gp = g_c + c * 1024 + wv * 256 + lane * 4;
        float*       lp = s_c + c * 1024 + wv * 256;
        __builtin_amdgcn_global_load_lds(
            (const __attribute__((address_space(1))) void*)gp,
            (__attribute__((address_space(3))) void*)lp, 16, 0, 0);
    }

    // Per-m scalar weights (wave-uniform -> scalar loads, off VMEM path).
    float wmv[MM], w2v[MM];
#pragma unroll
    for (int m = 0; m < MM; ++m) { wmv[m] = g_w[m]; w2v[m] = g_w255[m]; }

    const size_t rowoff = (size_t)tsrc * (NXX * NYY) + (size_t)i * NYY + (size_t)k0;

    float4 st[MM];
    // Issue channel-1 misses BEFORE the barrier: the vmcnt(0) drain the
    // barrier forces then covers both the DMA and these loads.
#pragma unroll
    for (int m = 0; m < MM; ++m)
        st[m] = *(const float4*)(c1 + (size_t)m * (TSOL * NXX * NYY) + rowoff);

    __syncthreads();

    float4 acc1 = {0.f, 0.f, 0.f, 0.f};
    float4 acc2 = {0.f, 0.f, 0.f, 0.f};

    // ---- channel 1: consume in issue order; weights from LDS ----
#pragma unroll
    for (int m = 0; m < MM; ++m) {
        float4 s = st[m];
        float lft = __shfl_up(s.w, 1);         // src[k0-1]; lane0: weight +0
        float rgt = __shfl_down(s.x, 1);       // src[k0+4]; lane63: weight -0
        float4 c  = *(const float4*)&s_c[m * NOUTT + k0];
        float wm_ = wmv[m];
        float w_w = l63 ? w2v[m] : wm_;        // k=255 knife edge
        acc1.x += wm_ * s.x + fabsf(c.x) * (((__float_as_int(c.x) >= 0) ? s.y : lft) - s.x);
        acc1.y += wm_ * s.y + fabsf(c.y) * (((__float_as_int(c.y) >= 0) ? s.z : s.x) - s.y);
        acc1.z += wm_ * s.z + fabsf(c.z) * (((__float_as_int(c.z) >= 0) ? s.w : s.y) - s.z);
        acc1.w += w_w * s.w + fabsf(c.w) * (((__float_as_int(c.w) >= 0) ? rgt : s.z) - s.w);
    }

    // ---- channel 2: batch, then consume ----
#pragma unroll
    for (int m = 0; m < MM; ++m)
        st[m] = *(const float4*)(c2 + (size_t)m * (TSOL * NXX * NYY) + rowoff);
#pragma unroll
    for (int m = 0; m < MM; ++m) {
        float4 s = st[m];
        float lft = __shfl_up(s.w, 1);
        float rgt = __shfl_down(s.x, 1);
        float4 c  = *(const float4*)&s_c[m * NOUTT + k0];
        float wm_ = wmv[m];
        float w_w = l63 ? w2v[m] : wm_;
        acc2.x += wm_ * s.x + fabsf(c.x) * (((__float_as_int(c.x) >= 0) ? s.y : lft) - s.x);
        acc2.y += wm_ * s.y + fabsf(c.y) * (((__float_as_int(c.y) >= 0) ? s.z : s.x) - s.y);
        acc2.z += wm_ * s.z + fabsf(c.z) * (((__float_as_int(c.z) >= 0) ? s.w : s.y) - s.z);
        acc2.w += w_w * s.w + fabsf(c.w) * (((__float_as_int(c.w) >= 0) ? rgt : s.z) - s.w);
    }

    if (lane == 0) acc1.x = 0.001f;            // c1[:,:,0]  = C_CU_TARGET
    if (l63)       acc2.w = 0.0001f;           // c2[:,:,-1] = C_NI_TARGET

    *(float4*)&out[((size_t)t * NOUTT + (size_t)i) * NOUTT + (size_t)k0] = acc1;
    *(float4*)&out[((size_t)(NTT + t) * NOUTT + (size_t)i) * NOUTT + (size_t)k0] = acc2;
}

extern "C" void kernel_launch(void* const* d_in, const int* in_sizes, int n_in,
                              void* d_out, int out_size, void* d_ws, size_t ws_size,
                              hipStream_t stream) {
    const float* params = (const float*)d_in[0];
    const float* c1     = (const float*)d_in[1];
    const float* c2     = (const float*)d_in[2];
    const float* Wq     = (const float*)d_in[3];
    const float* bq     = (const float*)d_in[4];
    const float* Wk     = (const float*)d_in[5];
    const float* bk     = (const float*)d_in[6];
    float* out = (float*)d_out;

    ai_setup_kernel<<<dim3(MM), dim3(256), 0, stream>>>(params, Wq, bq, Wk, bk);
    ai_resample_kernel<<<dim3(NOUTT / 4, NTT), dim3(256), 0, stream>>>(c1, c2, out);
}